// Round 1
// baseline (76.284 us; speedup 1.0000x reference)
//
#include <hip/hip_runtime.h>
#include <hip/hip_bf16.h>

#define NB 64    // batch
#define NT 128   // tokens (seq)
#define NE 4     // experts
#define ND 128   // model dim
#define NK 512   // ffn hidden dim

typedef __attribute__((ext_vector_type(8))) short bf16x8;
typedef __attribute__((ext_vector_type(4))) float f32x4;

__device__ __forceinline__ short f2bf(float f) {
    union { float f; unsigned u; } v; v.f = f;
    unsigned r = v.u + 0x7FFFu + ((v.u >> 16) & 1u);
    return (short)(r >> 16);
}

__device__ __forceinline__ float gelu_erf(float x) {
    return 0.5f * x * (1.0f + erff(x * 0.70710678118654752f));
}

// One block per (t, e). 256 threads = 4 waves.
// GEMM1: X_t [64 x 128] * W1 [128 x 512] -> H (gelu, bf16 in LDS)
// GEMM2: H [64 x 512] * W2 [512 x 128] -> gate-weighted contribution.
__global__ __launch_bounds__(256, 2)
void moe_main(const float* __restrict__ x,
              const float* __restrict__ w1,
              const float* __restrict__ b1,
              const float* __restrict__ w2,
              const float* __restrict__ b2,
              const float* __restrict__ rw,
              const float* __restrict__ rb,
              float* __restrict__ out,
              float* __restrict__ ws,
              int use_ws)
{
    const int blk  = blockIdx.x;
    const int t    = blk >> 2;
    const int e    = blk & 3;
    const int tid  = threadIdx.x;
    const int lane = tid & 63;
    const int wave = tid >> 6;
    const int l15  = lane & 15;
    const int l4   = lane >> 4;

    __shared__ short Hs[NB][NK + 8];   // bf16 bits, 64 x 520 -> 66,560 B (16B-aligned rows)
    __shared__ float gate_s[NB];

    // ---------------- gates (wave 0, one thread per batch row) ----------------
    if (tid < NB) {
        const int b = tid;
        const float* xr = x + (b * NT + t) * ND;
        float l0 = rb[0], l1 = rb[1], l2 = rb[2], l3 = rb[3];
        #pragma unroll 8
        for (int d = 0; d < ND; ++d) {
            const float xv = xr[d];
            const float* w = rw + d * NE;
            l0 += xv * w[0]; l1 += xv * w[1]; l2 += xv * w[2]; l3 += xv * w[3];
        }
        l0 = fmaxf(l0, 0.f); l1 = fmaxf(l1, 0.f); l2 = fmaxf(l2, 0.f); l3 = fmaxf(l3, 0.f);
        const float s   = l0 + l1 + l2 + l3;
        const float inv = 1.f / (s + 1e-9f);
        const float ge  = (e == 0) ? l0 : (e == 1) ? l1 : (e == 2) ? l2 : l3;
        gate_s[b] = ge * inv;
        if (e == 0) {
            float aux = s * inv;   // sum of normalized gates for this token
            #pragma unroll
            for (int off = 32; off > 0; off >>= 1) aux += __shfl_down(aux, off);
            if (lane == 0) atomicAdd(out + NB * NT * ND, aux * (0.01f / (NB * NT)));
        }
    }
    __syncthreads();

    // ---------------- GEMM1: wave owns N-stripe of 128 cols ----------------
    const float* W1 = w1 + (size_t)((t * NE + e) * ND) * NK;  // [ND][NK]
    const float* B1 = b1 + (t * NE + e) * NK;
    const int n0 = wave * 128;

    f32x4 acc[4][8];
    #pragma unroll
    for (int m = 0; m < 4; ++m)
        #pragma unroll
        for (int n = 0; n < 8; ++n) acc[m][n] = (f32x4){0.f, 0.f, 0.f, 0.f};

    #pragma unroll
    for (int ks = 0; ks < 4; ++ks) {
        const int d0 = ks * 32 + l4 * 8;   // contraction (D) offset for this lane
        bf16x8 afr[4];
        #pragma unroll
        for (int m = 0; m < 4; ++m) {
            const int b = m * 16 + l15;    // A row = batch index
            const float* xp = x + (b * NT + t) * ND + d0;
            const float4 u = *(const float4*)(xp);
            const float4 v = *(const float4*)(xp + 4);
            bf16x8 a;
            a[0] = f2bf(u.x); a[1] = f2bf(u.y); a[2] = f2bf(u.z); a[3] = f2bf(u.w);
            a[4] = f2bf(v.x); a[5] = f2bf(v.y); a[6] = f2bf(v.z); a[7] = f2bf(v.w);
            afr[m] = a;
        }
        #pragma unroll
        for (int nt = 0; nt < 8; ++nt) {
            const int n = n0 + nt * 16 + l15;          // B col = ffn unit
            const float* wp = W1 + (size_t)d0 * NK + n;
            bf16x8 bfr;
            #pragma unroll
            for (int j = 0; j < 8; ++j) bfr[j] = f2bf(wp[(size_t)j * NK]);
            #pragma unroll
            for (int m = 0; m < 4; ++m)
                acc[m][nt] = __builtin_amdgcn_mfma_f32_16x16x32_bf16(afr[m], bfr, acc[m][nt], 0, 0, 0);
        }
    }

    // bias + exact-erf gelu -> bf16 H in LDS
    #pragma unroll
    for (int nt = 0; nt < 8; ++nt) {
        const int n = n0 + nt * 16 + l15;
        const float bb = B1[n];
        #pragma unroll
        for (int m = 0; m < 4; ++m) {
            const int row = m * 16 + l4 * 4;
            #pragma unroll
            for (int r = 0; r < 4; ++r) {
                const float h = acc[m][nt][r] + bb;
                Hs[row + r][n] = f2bf(gelu_erf(h));
            }
        }
    }
    __syncthreads();

    // ---------------- GEMM2: wave owns 32 output cols ----------------
    const float* W2 = w2 + (size_t)((t * NE + e) * NK) * ND;  // [NK][ND]
    const float* B2 = b2 + (t * NE + e) * ND;
    const int c0 = wave * 32;

    f32x4 acc2[4][2];
    #pragma unroll
    for (int m = 0; m < 4; ++m)
        #pragma unroll
        for (int n = 0; n < 2; ++n) acc2[m][n] = (f32x4){0.f, 0.f, 0.f, 0.f};

    #pragma unroll 4
    for (int ks = 0; ks < 16; ++ks) {
        const int k0 = ks * 32 + l4 * 8;   // contraction (ffn) offset
        bf16x8 afr[4];
        #pragma unroll
        for (int m = 0; m < 4; ++m)
            afr[m] = *(const bf16x8*)(&Hs[m * 16 + l15][k0]);
        #pragma unroll
        for (int nt = 0; nt < 2; ++nt) {
            const int c = c0 + nt * 16 + l15;          // output dim
            const float* wp = W2 + (size_t)k0 * ND + c;
            bf16x8 bfr;
            #pragma unroll
            for (int j = 0; j < 8; ++j) bfr[j] = f2bf(wp[(size_t)j * ND]);
            #pragma unroll
            for (int m = 0; m < 4; ++m)
                acc2[m][nt] = __builtin_amdgcn_mfma_f32_16x16x32_bf16(afr[m], bfr, acc2[m][nt], 0, 0, 0);
        }
    }

    // gate-weighted epilogue
    #pragma unroll
    for (int nt = 0; nt < 2; ++nt) {
        const int c = c0 + nt * 16 + l15;
        const float bb = B2[c];
        #pragma unroll
        for (int m = 0; m < 4; ++m) {
            #pragma unroll
            for (int r = 0; r < 4; ++r) {
                const int b = m * 16 + l4 * 4 + r;
                const float v = (acc2[m][nt][r] + bb) * gate_s[b];
                if (use_ws) ws[(size_t)(e * NB * NT + b * NT + t) * ND + c] = v;
                else        atomicAdd(out + (size_t)(b * NT + t) * ND + c, v);
            }
        }
    }
}

__global__ __launch_bounds__(256)
void moe_reduce(const float* __restrict__ ws, float* __restrict__ out)
{
    const int i = blockIdx.x * blockDim.x + threadIdx.x;  // over BTD/4 float4s
    const int stride = NB * NT * ND / 4;
    const float4* w = (const float4*)ws;
    const float4 a = w[i];
    const float4 b = w[i + stride];
    const float4 c = w[i + 2 * stride];
    const float4 d = w[i + 3 * stride];
    float4 r;
    r.x = a.x + b.x + c.x + d.x;
    r.y = a.y + b.y + c.y + d.y;
    r.z = a.z + b.z + c.z + d.z;
    r.w = a.w + b.w + c.w + d.w;
    ((float4*)out)[i] = r;
}

extern "C" void kernel_launch(void* const* d_in, const int* in_sizes, int n_in,
                              void* d_out, int out_size, void* d_ws, size_t ws_size,
                              hipStream_t stream) {
    const float* x  = (const float*)d_in[0];
    const float* w1 = (const float*)d_in[1];
    const float* b1 = (const float*)d_in[2];
    const float* w2 = (const float*)d_in[3];
    const float* b2 = (const float*)d_in[4];
    const float* rw = (const float*)d_in[5];
    const float* rb = (const float*)d_in[6];
    float* out = (float*)d_out;

    const size_t ws_need = (size_t)NE * NB * NT * ND * sizeof(float);  // 16 MiB
    const int use_ws = (ws_size >= ws_need) ? 1 : 0;

    if (use_ws) {
        hipMemsetAsync(out + NB * NT * ND, 0, sizeof(float), stream);  // aux slot
    } else {
        hipMemsetAsync(d_out, 0, (size_t)(NB * NT * ND + 1) * sizeof(float), stream);
    }

    moe_main<<<NT * NE, 256, 0, stream>>>(x, w1, b1, w2, b2, rw, rb, out,
                                          (float*)d_ws, use_ws);
    if (use_ws) {
        moe_reduce<<<(NB * NT * ND / 4) / 256, 256, 0, stream>>>((const float*)d_ws, out);
    }
}